// Round 1
// baseline (665.532 us; speedup 1.0000x reference)
//
#include <hip/hip_runtime.h>
#include <hip/hip_bf16.h>
#include <stdint.h>

#define HH 512
#define BB 32
#define SSEQ 256
#define TVOC 50003
#define EPSF 1e-10f
#define EMSCALE 96.0f
// 255*ln(512) + 256*ln(96)
#define TOTLOG 2759.2459164008406f

typedef float f32x4 __attribute__((ext_vector_type(4)));
typedef int v8i __attribute__((ext_vector_type(8)));

__device__ __forceinline__ float wave_max(float v) {
#pragma unroll
  for (int off = 32; off; off >>= 1) v = fmaxf(v, __shfl_xor(v, off));
  return v;
}
__device__ __forceinline__ float wave_sum(float v) {
#pragma unroll
  for (int off = 32; off; off >>= 1) v += __shfl_xor(v, off);
  return v;
}

// ---------------------------------------------------------------- ws init
__global__ __launch_bounds__(512) void init_ws_kernel(float* ws) {
  if (threadIdx.x < 8) ws[threadIdx.x] = 0.0f;
  ws[8 + threadIdx.x] = 0.0f;
}

// ---------------------------------------------------------------- pi softmax
__global__ __launch_bounds__(512) void softmax_pi_kernel(
    const float* __restrict__ x, float* __restrict__ pi) {
  const int tid = threadIdx.x;
  const int wv = tid >> 6, ln = tid & 63;
  __shared__ float red[8];
  float v = x[tid];
  float m = wave_max(v);
  if (ln == 0) red[wv] = m;
  __syncthreads();
  float M = red[0];
#pragma unroll
  for (int i = 1; i < 8; ++i) M = fmaxf(M, red[i]);
  float e = __expf(v - M);
  float s = wave_sum(e);
  __syncthreads();
  if (ln == 0) red[wv] = s;
  __syncthreads();
  float S = 0.f;
#pragma unroll
  for (int i = 0; i < 8; ++i) S += red[i];
  pi[tid] = e / S;
}

// ---------------------------------------------------------------- A softmax + entropy
__global__ __launch_bounds__(512) void softmaxA_kernel(
    const float* __restrict__ tl, float* __restrict__ outA,
    float* __restrict__ ws_ent) {
  const int r = blockIdx.x, tid = threadIdx.x;
  const int wv = tid >> 6, ln = tid & 63;
  __shared__ float red[8];
  float v = tl[(size_t)r * HH + tid];
  float m = wave_max(v);
  if (ln == 0) red[wv] = m;
  __syncthreads();
  float M = red[0];
#pragma unroll
  for (int i = 1; i < 8; ++i) M = fmaxf(M, red[i]);
  float e = __expf(v - M);
  float s = wave_sum(e);
  __syncthreads();
  if (ln == 0) red[wv] = s;
  __syncthreads();
  float S = 0.f;
#pragma unroll
  for (int i = 0; i < 8; ++i) S += red[i];
  float p = e / S;
  outA[(size_t)r * HH + tid] = p;
  float ent = -p * __logf(p + EPSF);
  ent = wave_sum(ent);
  __syncthreads();
  if (ln == 0) red[wv] = ent;
  __syncthreads();
  if (tid == 0) {
    float tot = 0.f;
#pragma unroll
    for (int i = 0; i < 8; ++i) tot += red[i];
    atomicAdd(ws_ent, tot);
  }
}

// ---------------------------------------------------------------- partial column sums
__global__ __launch_bounds__(512) void colsum_partial_kernel(
    const float* __restrict__ outA, float* __restrict__ col) {
  const int j = threadIdx.x;
  const int i0 = blockIdx.x * 64;
  float s = 0.f;
#pragma unroll 4
  for (int i = i0; i < i0 + 64; ++i) s += outA[(size_t)i * HH + j];
  atomicAdd(&col[j], s);
}

// ---------------------------------------------------------------- B softmax + fused emission gather
// ems layout (bf16, viewed as uint2 = 4 values): [s][j>>2][b][j&3]
// so the scan can load 4 consecutive-j emissions per batch as one 8B load.
__global__ __launch_bounds__(1024) void softmaxB_gather_kernel(
    const float* __restrict__ el, float* __restrict__ outB,
    const int* __restrict__ tok, __hip_bfloat16* __restrict__ ems) {
  const int r = blockIdx.x, tid = threadIdx.x;
  const float* x = el + (size_t)r * TVOC;
  float* yo = outB + (size_t)r * TVOC;
  const int mis = (int)(((16u - ((unsigned)(uintptr_t)x & 15u)) & 15u) >> 2);
  const int body = (TVOC - mis) >> 2;
  const int tailoff = mis + body * 4;

  // 4 independent online (m,s) chains for ILP (serial exp chain was 49 deep)
  float m0 = -1e30f, s0 = 0.f, m1 = -1e30f, s1 = 0.f;
  float m2 = -1e30f, s2 = 0.f, m3 = -1e30f, s3 = 0.f;
  auto upd = [](float& m, float& s, float v) {
    if (v > m) { s = s * __expf(m - v) + 1.f; m = v; }
    else       { s += __expf(v - m); }
  };
  if (tid < mis) upd(m0, s0, x[tid]);
  const float4* x4 = (const float4*)(x + mis);
  for (int i = tid; i < body; i += 1024) {
    float4 v = x4[i];
    upd(m0, s0, v.x); upd(m1, s1, v.y); upd(m2, s2, v.z); upd(m3, s3, v.w);
  }
  for (int i = tailoff + tid; i < TVOC; i += 1024) upd(m0, s0, x[i]);
  auto mrg = [](float& m, float& s, float om, float os) {
    float nm = fmaxf(m, om);
    s = s * __expf(m - nm) + os * __expf(om - nm);
    m = nm;
  };
  mrg(m0, s0, m1, s1); mrg(m2, s2, m3, s3); mrg(m0, s0, m2, s2);
  float m = m0, s = s0;

  // wave-level (m,s) merge
#pragma unroll
  for (int off = 32; off; off >>= 1) {
    float om = __shfl_down(m, off), os = __shfl_down(s, off);
    float nm = fmaxf(m, om);
    s = s * __expf(m - nm) + os * __expf(om - nm);
    m = nm;
  }
  __shared__ float sm[16], ssv[16];
  __shared__ float bM, biZ;
  if ((tid & 63) == 0) { sm[tid >> 6] = m; ssv[tid >> 6] = s; }
  __syncthreads();
  if (tid == 0) {
    float M = sm[0], S = ssv[0];
#pragma unroll
    for (int w = 1; w < 16; ++w) {
      float nm = fmaxf(M, sm[w]);
      S = S * __expf(M - nm) + ssv[w] * __expf(sm[w] - nm);
      M = nm;
    }
    bM = M; biZ = 1.f / S;
  }
  __syncthreads();
  const float M = bM, iZ = biZ;
  if (tid < mis) yo[tid] = __expf(x[tid] - M) * iZ;
  float4* y4 = (float4*)(yo + mis);
  for (int i = tid; i < body; i += 1024) {
    float4 v = x4[i];
    float4 o;
    o.x = __expf(v.x - M) * iZ;
    o.y = __expf(v.y - M) * iZ;
    o.z = __expf(v.z - M) * iZ;
    o.w = __expf(v.w - M) * iZ;
    y4[i] = o;
  }
  for (int i = tailoff + tid; i < TVOC; i += 1024)
    yo[i] = __expf(x[i] - M) * iZ;

  // fused gather into grouped layout
  const float gs = EMSCALE * iZ;
  const int rg = r >> 2, rl = r & 3;
  for (int idx = tid; idx < BB * SSEQ; idx += 1024) {
    const int sq = idx >> 5, b = idx & 31;
    const int t = tok[b * SSEQ + sq];
    ems[((size_t)(sq * 128 + rg) * 32 + b) * 4 + rl] =
        __float2bfloat16(__expf(x[t] - M) * gs);
  }
}

// ---------------------------------------------------------------- forward scan
// 2 WGs x 512 threads (8 waves). WG h owns batches [h*16, h*16+16).
// Wave owns j-tile [wave*64, wave*64+64) -> each LDS B-fragment read is reused
// by 4 A-subtiles (halves per-step LDS traffic vs 16-wave/32-j config).
// A resident in VGPRs as fp8 e4m3 K=128 fragments (128 VGPRs/thread).
// alpha fp8 in LDS, double-buffered, rows padded to 528 B.
// Emissions pre-scaled by EMSCALE; renorm every 16 steps.
__global__ __launch_bounds__(512, 2) void scan_kernel(
    const float* __restrict__ d_pi, const float* __restrict__ d_A,
    const __hip_bfloat16* __restrict__ ems, float* __restrict__ ws_negll) {
  const int h = blockIdx.x;
  const int tid = threadIdx.x;
  const int lane = tid & 63;
  const int wave = tid >> 6;   // 0..7
  const int l15 = lane & 15;
  const int quad = lane >> 4;  // 0..3
  const int bG = h * 16 + l15; // global batch column

  __shared__ __align__(16) unsigned char alpha[2][16][528];
  __shared__ float wmax[8][17];
  __shared__ float wsum[8][17];
  __shared__ float ls[16];

  const unsigned short* emsu = (const unsigned short*)ems;
  const uint2* emv = (const uint2*)ems;  // 4 bf16 per uint2

  // ---- resident A fragments: aF[n][c]; j = wave*64 + n*16 + l15,
  // k byte p of chunk c <-> k = c*128 + quad*32 + p
  v8i aF[4][4];
#pragma unroll
  for (int n = 0; n < 4; ++n) {
    const int jg = wave * 64 + n * 16 + l15;
#pragma unroll
    for (int c = 0; c < 4; ++c) {
#pragma unroll
      for (int g = 0; g < 8; ++g) {
        const int k0 = c * 128 + quad * 32 + g * 4;
        const float v0 = d_A[(size_t)(k0 + 0) * HH + jg] * 512.0f;
        const float v1 = d_A[(size_t)(k0 + 1) * HH + jg] * 512.0f;
        const float v2 = d_A[(size_t)(k0 + 2) * HH + jg] * 512.0f;
        const float v3 = d_A[(size_t)(k0 + 3) * HH + jg] * 512.0f;
        int wrd = 0;
        wrd = __builtin_amdgcn_cvt_pk_fp8_f32(v0, v1, wrd, false);
        wrd = __builtin_amdgcn_cvt_pk_fp8_f32(v2, v3, wrd, true);
        aF[n][c][g] = wrd;
      }
    }
  }

  // ---- t = 0 init: each wave inits 2 batches
#pragma unroll
  for (int it = 0; it < 2; ++it) {
    const int b = wave * 2 + it;       // local batch 0..15
    const int bb = h * 16 + b;
    const int j0 = lane * 8;
    float vals[8];
    float m = -1e30f;
#pragma unroll
    for (int u = 0; u < 8; ++u) {
      const int j = j0 + u;
      const unsigned ew = (unsigned)emsu[((size_t)(j >> 2) * 32 + bb) * 4 + (j & 3)] << 16;
      vals[u] = (d_pi[j] + EPSF) * __uint_as_float(ew);
      m = fmaxf(m, vals[u]);
    }
    m = wave_max(m);
    if (lane == 0) ls[b] = __logf(m);
    const float r = 1.0f / m;
    int lo = 0, hi = 0;
    lo = __builtin_amdgcn_cvt_pk_fp8_f32(vals[0] * r, vals[1] * r, lo, false);
    lo = __builtin_amdgcn_cvt_pk_fp8_f32(vals[2] * r, vals[3] * r, lo, true);
    hi = __builtin_amdgcn_cvt_pk_fp8_f32(vals[4] * r, vals[5] * r, hi, false);
    hi = __builtin_amdgcn_cvt_pk_fp8_f32(vals[6] * r, vals[7] * r, hi, true);
    *(unsigned int*)&alpha[0][b][j0]     = (unsigned)lo;
    *(unsigned int*)&alpha[0][b][j0 + 4] = (unsigned)hi;
  }
  __syncthreads();

  // ---- emission prefetch: thread base group g0 = wave*16 + quad, subtile n
  // adds n*4 groups = n*128 uint2 (imm offset). Per-step stride 128*32 uint2.
  const uint2* ep = emv + ((size_t)1 * 128 + wave * 16 + quad) * 32 + bG;
  uint2 evr[4];
#pragma unroll
  for (int n = 0; n < 4; ++n) evr[n] = ep[n * 128];
  ep += 128 * 32;  // -> s = 2

#pragma unroll 2
  for (int t = 1; t < SSEQ; ++t) {
    const int cur = (t - 1) & 1, nxt = t & 1;

    // decode this step's emissions (loaded last iteration)
    float ev[4][4];
#pragma unroll
    for (int n = 0; n < 4; ++n) {
      ev[n][0] = __uint_as_float(evr[n].x << 16);
      ev[n][1] = __uint_as_float(evr[n].x & 0xFFFF0000u);
      ev[n][2] = __uint_as_float(evr[n].y << 16);
      ev[n][3] = __uint_as_float(evr[n].y & 0xFFFF0000u);
    }
    // prefetch t+1 (pointer held at last valid step)
#pragma unroll
    for (int n = 0; n < 4; ++n) evr[n] = ep[n * 128];
    if (t <= SSEQ - 3) ep += 128 * 32;

    f32x4 acc0 = {0.f, 0.f, 0.f, 0.f}, acc1 = {0.f, 0.f, 0.f, 0.f};
    f32x4 acc2 = {0.f, 0.f, 0.f, 0.f}, acc3 = {0.f, 0.f, 0.f, 0.f};
#pragma unroll
    for (int c = 0; c < 4; ++c) {
      const unsigned char* ap = &alpha[cur][l15][c * 128 + quad * 32];
      v8i bf;
      *(int4*)&bf       = *(const int4*)ap;
      *(((int4*)&bf)+1) = *(const int4*)(ap + 16);
      acc0 = __builtin_amdgcn_mfma_scale_f32_16x16x128_f8f6f4(
          aF[0][c], bf, acc0, 0, 0, 0, 0x7F7F7F7F, 0, 0x7F7F7F7F);
      acc1 = __builtin_amdgcn_mfma_scale_f32_16x16x128_f8f6f4(
          aF[1][c], bf, acc1, 0, 0, 0, 0x7F7F7F7F, 0, 0x7F7F7F7F);
      acc2 = __builtin_amdgcn_mfma_scale_f32_16x16x128_f8f6f4(
          aF[2][c], bf, acc2, 0, 0, 0, 0x7F7F7F7F, 0, 0x7F7F7F7F);
      acc3 = __builtin_amdgcn_mfma_scale_f32_16x16x128_f8f6f4(
          aF[3][c], bf, acc3, 0, 0, 0, 0x7F7F7F7F, 0, 0x7F7F7F7F);
    }

    // D layout: col(b)=lane&15, row(j within subtile)=quad*4+rg
    float y[4][4];
#pragma unroll
    for (int rg = 0; rg < 4; ++rg) {
      y[0][rg] = acc0[rg] * ev[0][rg];
      y[1][rg] = acc1[rg] * ev[1][rg];
      y[2][rg] = acc2[rg] * ev[2][rg];
      y[3][rg] = acc3[rg] * ev[3][rg];
    }

    float r = 1.0f;
    if ((t & 15) == 0) {  // renorm: global per-batch max + log accounting
      float mm = -1e30f;
#pragma unroll
      for (int n = 0; n < 4; ++n)
#pragma unroll
        for (int rg = 0; rg < 4; ++rg) mm = fmaxf(mm, y[n][rg]);
      mm = fmaxf(mm, __shfl_xor(mm, 16));
      mm = fmaxf(mm, __shfl_xor(mm, 32));
      if (lane < 16) wmax[wave][lane] = mm;
      __syncthreads();
      float m = wmax[0][l15];
#pragma unroll
      for (int w = 1; w < 8; ++w) m = fmaxf(m, wmax[w][l15]);
      r = 1.0f / m;
      if (tid < 16) ls[tid] += __logf(m);
    }

#pragma unroll
    for (int n = 0; n < 4; ++n) {
      int d = 0;
      d = __builtin_amdgcn_cvt_pk_fp8_f32(y[n][0] * r, y[n][1] * r, d, false);
      d = __builtin_amdgcn_cvt_pk_fp8_f32(y[n][2] * r, y[n][3] * r, d, true);
      *(unsigned int*)&alpha[nxt][l15][wave * 64 + n * 16 + quad * 4] = (unsigned)d;
    }
    if (t == SSEQ - 1) {
      float s = 0.f;
#pragma unroll
      for (int n = 0; n < 4; ++n) s += y[n][0] + y[n][1] + y[n][2] + y[n][3];
      s *= r;
      s += __shfl_xor(s, 16);
      s += __shfl_xor(s, 32);
      if (lane < 16) wsum[wave][lane] = s;
    }
    __syncthreads();
  }

  if (wave == 0 && lane < 16) {
    float s = 0.f;
#pragma unroll
    for (int w = 0; w < 8; ++w) s += wsum[w][lane];
    const float LL = __logf(s) + ls[lane] - TOTLOG;
    atomicAdd(ws_negll, -LL * (1.0f / 32.0f));
  }
}

// ---------------------------------------------------------------- finalize loss
__global__ __launch_bounds__(512) void finalize_kernel(
    const float* __restrict__ ws, const float* __restrict__ col,
    const float* __restrict__ thr, float* __restrict__ out_loss) {
  const int j = threadIdx.x;
  float v = fmaxf(thr[0] - col[j], 0.f);
  v = wave_sum(v);
  __shared__ float red[8];
  if ((j & 63) == 0) red[j >> 6] = v;
  __syncthreads();
  if (j == 0) {
    float creg = 0.f;
#pragma unroll
    for (int i = 0; i < 8; ++i) creg += red[i];
    out_loss[0] = ws[1] + ws[0] * (0.1f / 512.0f) + creg;
  }
}

// ----------------------------------------------------------------
extern "C" void kernel_launch(void* const* d_in, const int* in_sizes, int n_in,
                              void* d_out, int out_size, void* d_ws, size_t ws_size,
                              hipStream_t stream) {
  const int*   tok    = (const int*)d_in[0];    // [32,256]
  const float* initl  = (const float*)d_in[1];  // [512]
  const float* transl = (const float*)d_in[2];  // [512,512]
  const float* eml    = (const float*)d_in[3];  // [512,50003]
  const float* thr    = (const float*)d_in[4];  // scalar

  float* out      = (float*)d_out;
  float* out_pi   = out;
  float* out_A    = out + HH;
  float* out_B    = out + HH + (size_t)HH * HH;
  float* out_loss = out + HH + (size_t)HH * HH + (size_t)HH * TVOC;

  float* wsf = (float*)d_ws;           // [0..8) scalars, [8..520) col sums
  float* col = wsf + 8;
  __hip_bfloat16* ems = (__hip_bfloat16*)((char*)d_ws + 4096);  // 8.4 MB

  init_ws_kernel<<<1, 512, 0, stream>>>(wsf);
  softmax_pi_kernel<<<1, 512, 0, stream>>>(initl, out_pi);
  softmaxA_kernel<<<512, 512, 0, stream>>>(transl, out_A, wsf + 0);
  colsum_partial_kernel<<<8, 512, 0, stream>>>(out_A, col);
  softmaxB_gather_kernel<<<512, 1024, 0, stream>>>(eml, out_B, tok, ems);
  scan_kernel<<<2, 512, 0, stream>>>(out_pi, out_A, ems, wsf + 1);
  finalize_kernel<<<1, 512, 0, stream>>>(wsf, col, thr, out_loss);
}

// Round 2
// 573.898 us; speedup vs baseline: 1.1597x; 1.1597x over previous
//
#include <hip/hip_runtime.h>
#include <hip/hip_bf16.h>
#include <stdint.h>

#define HH 512
#define BB 32
#define SSEQ 256
#define TVOC 50003
#define EPSF 1e-10f
#define EMSCALE 96.0f
// 255*ln(512) + 256*ln(96)
#define TOTLOG 2759.2459164008406f

typedef float f32x4 __attribute__((ext_vector_type(4)));
typedef int v8i __attribute__((ext_vector_type(8)));

__device__ __forceinline__ float wave_max(float v) {
#pragma unroll
  for (int off = 32; off; off >>= 1) v = fmaxf(v, __shfl_xor(v, off));
  return v;
}
__device__ __forceinline__ float wave_sum(float v) {
#pragma unroll
  for (int off = 32; off; off >>= 1) v += __shfl_xor(v, off);
  return v;
}

// ---------------------------------------------------------------- ws init
__global__ __launch_bounds__(512) void init_ws_kernel(float* ws) {
  if (threadIdx.x < 8) ws[threadIdx.x] = 0.0f;
  ws[8 + threadIdx.x] = 0.0f;
}

// ---------------------------------------------------------------- pi softmax
__global__ __launch_bounds__(512) void softmax_pi_kernel(
    const float* __restrict__ x, float* __restrict__ pi) {
  const int tid = threadIdx.x;
  const int wv = tid >> 6, ln = tid & 63;
  __shared__ float red[8];
  float v = x[tid];
  float m = wave_max(v);
  if (ln == 0) red[wv] = m;
  __syncthreads();
  float M = red[0];
#pragma unroll
  for (int i = 1; i < 8; ++i) M = fmaxf(M, red[i]);
  float e = __expf(v - M);
  float s = wave_sum(e);
  __syncthreads();
  if (ln == 0) red[wv] = s;
  __syncthreads();
  float S = 0.f;
#pragma unroll
  for (int i = 0; i < 8; ++i) S += red[i];
  pi[tid] = e / S;
}

// ---------------------------------------------------------------- A softmax + entropy
__global__ __launch_bounds__(512) void softmaxA_kernel(
    const float* __restrict__ tl, float* __restrict__ outA,
    float* __restrict__ ws_ent) {
  const int r = blockIdx.x, tid = threadIdx.x;
  const int wv = tid >> 6, ln = tid & 63;
  __shared__ float red[8];
  float v = tl[(size_t)r * HH + tid];
  float m = wave_max(v);
  if (ln == 0) red[wv] = m;
  __syncthreads();
  float M = red[0];
#pragma unroll
  for (int i = 1; i < 8; ++i) M = fmaxf(M, red[i]);
  float e = __expf(v - M);
  float s = wave_sum(e);
  __syncthreads();
  if (ln == 0) red[wv] = s;
  __syncthreads();
  float S = 0.f;
#pragma unroll
  for (int i = 0; i < 8; ++i) S += red[i];
  float p = e / S;
  outA[(size_t)r * HH + tid] = p;
  float ent = -p * __logf(p + EPSF);
  ent = wave_sum(ent);
  __syncthreads();
  if (ln == 0) red[wv] = ent;
  __syncthreads();
  if (tid == 0) {
    float tot = 0.f;
#pragma unroll
    for (int i = 0; i < 8; ++i) tot += red[i];
    atomicAdd(ws_ent, tot);
  }
}

// ---------------------------------------------------------------- partial column sums
__global__ __launch_bounds__(512) void colsum_partial_kernel(
    const float* __restrict__ outA, float* __restrict__ col) {
  const int j = threadIdx.x;
  const int i0 = blockIdx.x * 64;
  float s = 0.f;
#pragma unroll 4
  for (int i = i0; i < i0 + 64; ++i) s += outA[(size_t)i * HH + j];
  atomicAdd(&col[j], s);
}

// ---------------------------------------------------------------- B softmax + fused emission gather
// ems layout (bf16, viewed as uint2 = 4 values): [s][j>>2][b][j&3]
// so the scan can load 4 consecutive-j emissions per batch as one 8B load.
__global__ __launch_bounds__(1024) void softmaxB_gather_kernel(
    const float* __restrict__ el, float* __restrict__ outB,
    const int* __restrict__ tok, __hip_bfloat16* __restrict__ ems) {
  const int r = blockIdx.x, tid = threadIdx.x;
  const float* x = el + (size_t)r * TVOC;
  float* yo = outB + (size_t)r * TVOC;
  const int mis = (int)(((16u - ((unsigned)(uintptr_t)x & 15u)) & 15u) >> 2);
  const int body = (TVOC - mis) >> 2;
  const int tailoff = mis + body * 4;

  // 4 independent online (m,s) chains for ILP
  float m0 = -1e30f, s0 = 0.f, m1 = -1e30f, s1 = 0.f;
  float m2 = -1e30f, s2 = 0.f, m3 = -1e30f, s3 = 0.f;
  auto upd = [](float& m, float& s, float v) {
    if (v > m) { s = s * __expf(m - v) + 1.f; m = v; }
    else       { s += __expf(v - m); }
  };
  if (tid < mis) upd(m0, s0, x[tid]);
  const float4* x4 = (const float4*)(x + mis);
  for (int i = tid; i < body; i += 1024) {
    float4 v = x4[i];
    upd(m0, s0, v.x); upd(m1, s1, v.y); upd(m2, s2, v.z); upd(m3, s3, v.w);
  }
  for (int i = tailoff + tid; i < TVOC; i += 1024) upd(m0, s0, x[i]);
  auto mrg = [](float& m, float& s, float om, float os) {
    float nm = fmaxf(m, om);
    s = s * __expf(m - nm) + os * __expf(om - nm);
    m = nm;
  };
  mrg(m0, s0, m1, s1); mrg(m2, s2, m3, s3); mrg(m0, s0, m2, s2);
  float m = m0, s = s0;

#pragma unroll
  for (int off = 32; off; off >>= 1) {
    float om = __shfl_down(m, off), os = __shfl_down(s, off);
    float nm = fmaxf(m, om);
    s = s * __expf(m - nm) + os * __expf(om - nm);
    m = nm;
  }
  __shared__ float sm[16], ssv[16];
  __shared__ float bM, biZ;
  if ((tid & 63) == 0) { sm[tid >> 6] = m; ssv[tid >> 6] = s; }
  __syncthreads();
  if (tid == 0) {
    float M = sm[0], S = ssv[0];
#pragma unroll
    for (int w = 1; w < 16; ++w) {
      float nm = fmaxf(M, sm[w]);
      S = S * __expf(M - nm) + ssv[w] * __expf(sm[w] - nm);
      M = nm;
    }
    bM = M; biZ = 1.f / S;
  }
  __syncthreads();
  const float M = bM, iZ = biZ;
  if (tid < mis) yo[tid] = __expf(x[tid] - M) * iZ;
  float4* y4 = (float4*)(yo + mis);
  for (int i = tid; i < body; i += 1024) {
    float4 v = x4[i];
    float4 o;
    o.x = __expf(v.x - M) * iZ;
    o.y = __expf(v.y - M) * iZ;
    o.z = __expf(v.z - M) * iZ;
    o.w = __expf(v.w - M) * iZ;
    y4[i] = o;
  }
  for (int i = tailoff + tid; i < TVOC; i += 1024)
    yo[i] = __expf(x[i] - M) * iZ;

  // fused gather into grouped layout
  const float gs = EMSCALE * iZ;
  const int rg = r >> 2, rl = r & 3;
  for (int idx = tid; idx < BB * SSEQ; idx += 1024) {
    const int sq = idx >> 5, b = idx & 31;
    const int t = tok[b * SSEQ + sq];
    ems[((size_t)(sq * 128 + rg) * 32 + b) * 4 + rl] =
        __float2bfloat16(__expf(x[t] - M) * gs);
  }
}

// ---------------------------------------------------------------- forward scan
// 2 WGs x 1024 threads (16 waves = 4/SIMD for latency hiding). WG h owns
// batches [h*16, h*16+16). Wave owns j-tile [wave*32, wave*32+32).
// A resident in regs as fp8 e4m3 K=128 fragments (64 regs/thread -> AGPRs).
// alpha fp8 in LDS, double-buffered, rows padded to 528 B.
// Emissions pre-scaled by EMSCALE, grouped [s][j>>2][b][4] so each thread's
// per-step emissions are 2x 8B loads with immediate offsets.
// Renorm (max + log accounting) every 16 steps only.
__global__ __launch_bounds__(1024) void scan_kernel(
    const float* __restrict__ d_pi, const float* __restrict__ d_A,
    const __hip_bfloat16* __restrict__ ems, float* __restrict__ ws_negll) {
  const int h = blockIdx.x;
  const int tid = threadIdx.x;
  const int lane = tid & 63;
  const int wave = tid >> 6;   // 0..15
  const int l15 = lane & 15;
  const int quad = lane >> 4;  // 0..3
  const int bG = h * 16 + l15; // global batch column

  __shared__ __align__(16) unsigned char alpha[2][16][528];
  __shared__ float wmax[16][17];
  __shared__ float wsum[16][17];
  __shared__ float ls[16];

  const uint2* emv = (const uint2*)ems;  // 4 bf16 per uint2

  // ---- resident A fragments: j = wave*32 + n*16 + l15,
  // k byte p of chunk c <-> k = c*128 + quad*32 + p
  v8i aF[2][4];
#pragma unroll
  for (int n = 0; n < 2; ++n) {
    const int jg = wave * 32 + n * 16 + l15;
#pragma unroll
    for (int c = 0; c < 4; ++c) {
#pragma unroll
      for (int g = 0; g < 8; ++g) {
        const int k0 = c * 128 + quad * 32 + g * 4;
        const float v0 = d_A[(size_t)(k0 + 0) * HH + jg] * 512.0f;
        const float v1 = d_A[(size_t)(k0 + 1) * HH + jg] * 512.0f;
        const float v2 = d_A[(size_t)(k0 + 2) * HH + jg] * 512.0f;
        const float v3 = d_A[(size_t)(k0 + 3) * HH + jg] * 512.0f;
        int wrd = 0;
        wrd = __builtin_amdgcn_cvt_pk_fp8_f32(v0, v1, wrd, false);
        wrd = __builtin_amdgcn_cvt_pk_fp8_f32(v2, v3, wrd, true);
        aF[n][c][g] = wrd;
      }
    }
  }

  // ---- t = 0 init: wave w handles batch b=w (global h*16+w)
  {
    const int b = wave;
    const int bb = h * 16 + b;
    const int j0 = lane * 8;
    const float4 p0 = *(const float4*)&d_pi[j0];
    const float4 p1 = *(const float4*)&d_pi[j0 + 4];
    const uint2 e0 = emv[(size_t)(2 * lane) * 32 + bb];
    const uint2 e1 = emv[(size_t)(2 * lane + 1) * 32 + bb];
    float em[8];
    em[0] = __uint_as_float(e0.x << 16);
    em[1] = __uint_as_float(e0.x & 0xFFFF0000u);
    em[2] = __uint_as_float(e0.y << 16);
    em[3] = __uint_as_float(e0.y & 0xFFFF0000u);
    em[4] = __uint_as_float(e1.x << 16);
    em[5] = __uint_as_float(e1.x & 0xFFFF0000u);
    em[6] = __uint_as_float(e1.y << 16);
    em[7] = __uint_as_float(e1.y & 0xFFFF0000u);
    float vals[8];
    vals[0] = (p0.x + EPSF) * em[0];
    vals[1] = (p0.y + EPSF) * em[1];
    vals[2] = (p0.z + EPSF) * em[2];
    vals[3] = (p0.w + EPSF) * em[3];
    vals[4] = (p1.x + EPSF) * em[4];
    vals[5] = (p1.y + EPSF) * em[5];
    vals[6] = (p1.z + EPSF) * em[6];
    vals[7] = (p1.w + EPSF) * em[7];
    float m = -1e30f;
#pragma unroll
    for (int u = 0; u < 8; ++u) m = fmaxf(m, vals[u]);
    m = wave_max(m);
    if (lane == 0) ls[b] = __logf(m);
    const float r = 1.0f / m;
    int lo = 0, hi = 0;
    lo = __builtin_amdgcn_cvt_pk_fp8_f32(vals[0] * r, vals[1] * r, lo, false);
    lo = __builtin_amdgcn_cvt_pk_fp8_f32(vals[2] * r, vals[3] * r, lo, true);
    hi = __builtin_amdgcn_cvt_pk_fp8_f32(vals[4] * r, vals[5] * r, hi, false);
    hi = __builtin_amdgcn_cvt_pk_fp8_f32(vals[6] * r, vals[7] * r, hi, true);
    *(unsigned int*)&alpha[0][b][j0]     = (unsigned)lo;
    *(unsigned int*)&alpha[0][b][j0 + 4] = (unsigned)hi;
  }
  __syncthreads();

  // ---- emission prefetch: thread base group g0 = wave*8 + quad; subtile n
  // adds n*4 groups = n*128 uint2 (imm offset). Per-step stride 128*32 uint2.
  const uint2* ep = emv + ((size_t)1 * 128 + wave * 8 + quad) * 32 + bG;
  uint2 evr[2];
#pragma unroll
  for (int n = 0; n < 2; ++n) evr[n] = ep[n * 128];
  ep += 128 * 32;  // -> s = 2

#pragma unroll 2
  for (int t = 1; t < SSEQ; ++t) {
    const int cur = (t - 1) & 1, nxt = t & 1;

    // decode this step's emissions (loaded last iteration)
    float ev[2][4];
#pragma unroll
    for (int n = 0; n < 2; ++n) {
      ev[n][0] = __uint_as_float(evr[n].x << 16);
      ev[n][1] = __uint_as_float(evr[n].x & 0xFFFF0000u);
      ev[n][2] = __uint_as_float(evr[n].y << 16);
      ev[n][3] = __uint_as_float(evr[n].y & 0xFFFF0000u);
    }
    // prefetch t+1 (pointer held at last valid step)
#pragma unroll
    for (int n = 0; n < 2; ++n) evr[n] = ep[n * 128];
    if (t <= SSEQ - 3) ep += 128 * 32;

    f32x4 acc0 = {0.f, 0.f, 0.f, 0.f}, acc1 = {0.f, 0.f, 0.f, 0.f};
#pragma unroll
    for (int c = 0; c < 4; ++c) {
      const unsigned char* ap = &alpha[cur][l15][c * 128 + quad * 32];
      v8i bf;
      *(int4*)&bf         = *(const int4*)ap;
      *(((int4*)&bf) + 1) = *(const int4*)(ap + 16);
      acc0 = __builtin_amdgcn_mfma_scale_f32_16x16x128_f8f6f4(
          aF[0][c], bf, acc0, 0, 0, 0, 0x7F7F7F7F, 0, 0x7F7F7F7F);
      acc1 = __builtin_amdgcn_mfma_scale_f32_16x16x128_f8f6f4(
          aF[1][c], bf, acc1, 0, 0, 0, 0x7F7F7F7F, 0, 0x7F7F7F7F);
    }

    // D layout: col(b)=lane&15, row(j within subtile)=quad*4+rg
    float y[2][4];
#pragma unroll
    for (int rg = 0; rg < 4; ++rg) {
      y[0][rg] = acc0[rg] * ev[0][rg];
      y[1][rg] = acc1[rg] * ev[1][rg];
    }

    float r = 1.0f;
    if ((t & 15) == 0) {  // renorm: global per-batch max + log accounting
      float mm = -1e30f;
#pragma unroll
      for (int n = 0; n < 2; ++n)
#pragma unroll
        for (int rg = 0; rg < 4; ++rg) mm = fmaxf(mm, y[n][rg]);
      mm = fmaxf(mm, __shfl_xor(mm, 16));
      mm = fmaxf(mm, __shfl_xor(mm, 32));
      if (lane < 16) wmax[wave][lane] = mm;
      __syncthreads();
      float m = wmax[0][l15];
#pragma unroll
      for (int w = 1; w < 16; ++w) m = fmaxf(m, wmax[w][l15]);
      r = 1.0f / m;
      if (tid < 16) ls[tid] += __logf(m);
    }

#pragma unroll
    for (int n = 0; n < 2; ++n) {
      int d = 0;
      d = __builtin_amdgcn_cvt_pk_fp8_f32(y[n][0] * r, y[n][1] * r, d, false);
      d = __builtin_amdgcn_cvt_pk_fp8_f32(y[n][2] * r, y[n][3] * r, d, true);
      *(unsigned int*)&alpha[nxt][l15][wave * 32 + n * 16 + quad * 4] = (unsigned)d;
    }
    if (t == SSEQ - 1) {
      float s = (y[0][0] + y[0][1] + y[0][2] + y[0][3] +
                 y[1][0] + y[1][1] + y[1][2] + y[1][3]) * r;
      s += __shfl_xor(s, 16);
      s += __shfl_xor(s, 32);
      if (lane < 16) wsum[wave][lane] = s;
    }
    __syncthreads();
  }

  if (wave == 0 && lane < 16) {
    float s = 0.f;
#pragma unroll
    for (int w = 0; w < 16; ++w) s += wsum[w][lane];
    const float LL = __logf(s) + ls[lane] - TOTLOG;
    atomicAdd(ws_negll, -LL * (1.0f / 32.0f));
  }
}

// ---------------------------------------------------------------- finalize loss
__global__ __launch_bounds__(512) void finalize_kernel(
    const float* __restrict__ ws, const float* __restrict__ col,
    const float* __restrict__ thr, float* __restrict__ out_loss) {
  const int j = threadIdx.x;
  float v = fmaxf(thr[0] - col[j], 0.f);
  v = wave_sum(v);
  __shared__ float red[8];
  if ((j & 63) == 0) red[j >> 6] = v;
  __syncthreads();
  if (j == 0) {
    float creg = 0.f;
#pragma unroll
    for (int i = 0; i < 8; ++i) creg += red[i];
    out_loss[0] = ws[1] + ws[0] * (0.1f / 512.0f) + creg;
  }
}

// ----------------------------------------------------------------
extern "C" void kernel_launch(void* const* d_in, const int* in_sizes, int n_in,
                              void* d_out, int out_size, void* d_ws, size_t ws_size,
                              hipStream_t stream) {
  const int*   tok    = (const int*)d_in[0];    // [32,256]
  const float* initl  = (const float*)d_in[1];  // [512]
  const float* transl = (const float*)d_in[2];  // [512,512]
  const float* eml    = (const float*)d_in[3];  // [512,50003]
  const float* thr    = (const float*)d_in[4];  // scalar

  float* out      = (float*)d_out;
  float* out_pi   = out;
  float* out_A    = out + HH;
  float* out_B    = out + HH + (size_t)HH * HH;
  float* out_loss = out + HH + (size_t)HH * HH + (size_t)HH * TVOC;

  float* wsf = (float*)d_ws;           // [0..8) scalars, [8..520) col sums
  float* col = wsf + 8;
  __hip_bfloat16* ems = (__hip_bfloat16*)((char*)d_ws + 4096);  // 8.4 MB

  init_ws_kernel<<<1, 512, 0, stream>>>(wsf);
  softmax_pi_kernel<<<1, 512, 0, stream>>>(initl, out_pi);
  softmaxA_kernel<<<512, 512, 0, stream>>>(transl, out_A, wsf + 0);
  colsum_partial_kernel<<<8, 512, 0, stream>>>(out_A, col);
  softmaxB_gather_kernel<<<512, 1024, 0, stream>>>(eml, out_B, tok, ems);
  scan_kernel<<<2, 1024, 0, stream>>>(out_pi, out_A, ems, wsf + 1);
  finalize_kernel<<<1, 512, 0, stream>>>(wsf, col, thr, out_loss);
}

// Round 5
// 568.150 us; speedup vs baseline: 1.1714x; 1.0101x over previous
//
#include <hip/hip_runtime.h>
#include <hip/hip_bf16.h>
#include <stdint.h>

#define HH 512
#define BB 32
#define SSEQ 256
#define TVOC 50003
#define EPSF 1e-10f
#define EMSCALE 96.0f
// 255*ln(512) + 256*ln(96)
#define TOTLOG 2759.2459164008406f

typedef float f32x4 __attribute__((ext_vector_type(4)));
typedef int v8i __attribute__((ext_vector_type(8)));

__device__ __forceinline__ float wave_max(float v) {
#pragma unroll
  for (int off = 32; off; off >>= 1) v = fmaxf(v, __shfl_xor(v, off));
  return v;
}
__device__ __forceinline__ float wave_sum(float v) {
#pragma unroll
  for (int off = 32; off; off >>= 1) v += __shfl_xor(v, off);
  return v;
}

// ---------------------------------------------------------------- ws init
__global__ __launch_bounds__(512) void init_ws_kernel(float* ws) {
  if (threadIdx.x < 8) ws[threadIdx.x] = 0.0f;
  ws[8 + threadIdx.x] = 0.0f;
}

// ---------------------------------------------------------------- pi softmax
__global__ __launch_bounds__(512) void softmax_pi_kernel(
    const float* __restrict__ x, float* __restrict__ pi) {
  const int tid = threadIdx.x;
  const int wv = tid >> 6, ln = tid & 63;
  __shared__ float red[8];
  float v = x[tid];
  float m = wave_max(v);
  if (ln == 0) red[wv] = m;
  __syncthreads();
  float M = red[0];
#pragma unroll
  for (int i = 1; i < 8; ++i) M = fmaxf(M, red[i]);
  float e = __expf(v - M);
  float s = wave_sum(e);
  __syncthreads();
  if (ln == 0) red[wv] = s;
  __syncthreads();
  float S = 0.f;
#pragma unroll
  for (int i = 0; i < 8; ++i) S += red[i];
  pi[tid] = e / S;
}

// ---------------------------------------------------------------- A softmax + entropy
__global__ __launch_bounds__(512) void softmaxA_kernel(
    const float* __restrict__ tl, float* __restrict__ outA,
    float* __restrict__ ws_ent) {
  const int r = blockIdx.x, tid = threadIdx.x;
  const int wv = tid >> 6, ln = tid & 63;
  __shared__ float red[8];
  float v = tl[(size_t)r * HH + tid];
  float m = wave_max(v);
  if (ln == 0) red[wv] = m;
  __syncthreads();
  float M = red[0];
#pragma unroll
  for (int i = 1; i < 8; ++i) M = fmaxf(M, red[i]);
  float e = __expf(v - M);
  float s = wave_sum(e);
  __syncthreads();
  if (ln == 0) red[wv] = s;
  __syncthreads();
  float S = 0.f;
#pragma unroll
  for (int i = 0; i < 8; ++i) S += red[i];
  float p = e / S;
  outA[(size_t)r * HH + tid] = p;
  float ent = -p * __logf(p + EPSF);
  ent = wave_sum(ent);
  __syncthreads();
  if (ln == 0) red[wv] = ent;
  __syncthreads();
  if (tid == 0) {
    float tot = 0.f;
#pragma unroll
    for (int i = 0; i < 8; ++i) tot += red[i];
    atomicAdd(ws_ent, tot);
  }
}

// ---------------------------------------------------------------- partial column sums
__global__ __launch_bounds__(512) void colsum_partial_kernel(
    const float* __restrict__ outA, float* __restrict__ col) {
  const int j = threadIdx.x;
  const int i0 = blockIdx.x * 64;
  float s = 0.f;
#pragma unroll 4
  for (int i = i0; i < i0 + 64; ++i) s += outA[(size_t)i * HH + j];
  atomicAdd(&col[j], s);
}

// ---------------------------------------------------------------- B softmax + fused emission gather
// ems layout (bf16, viewed as uint2 = 4 values): [s][j>>2][b][j&3]
__global__ __launch_bounds__(1024) void softmaxB_gather_kernel(
    const float* __restrict__ el, float* __restrict__ outB,
    const int* __restrict__ tok, __hip_bfloat16* __restrict__ ems) {
  const int r = blockIdx.x, tid = threadIdx.x;
  const float* x = el + (size_t)r * TVOC;
  float* yo = outB + (size_t)r * TVOC;
  const int mis = (int)(((16u - ((unsigned)(uintptr_t)x & 15u)) & 15u) >> 2);
  const int body = (TVOC - mis) >> 2;
  const int tailoff = mis + body * 4;

  // 4 independent online (m,s) chains for ILP
  float m0 = -1e30f, s0 = 0.f, m1 = -1e30f, s1 = 0.f;
  float m2 = -1e30f, s2 = 0.f, m3 = -1e30f, s3 = 0.f;
  auto upd = [](float& m, float& s, float v) {
    if (v > m) { s = s * __expf(m - v) + 1.f; m = v; }
    else       { s += __expf(v - m); }
  };
  if (tid < mis) upd(m0, s0, x[tid]);
  const float4* x4 = (const float4*)(x + mis);
  for (int i = tid; i < body; i += 1024) {
    float4 v = x4[i];
    upd(m0, s0, v.x); upd(m1, s1, v.y); upd(m2, s2, v.z); upd(m3, s3, v.w);
  }
  for (int i = tailoff + tid; i < TVOC; i += 1024) upd(m0, s0, x[i]);
  auto mrg = [](float& m, float& s, float om, float os) {
    float nm = fmaxf(m, om);
    s = s * __expf(m - nm) + os * __expf(om - nm);
    m = nm;
  };
  mrg(m0, s0, m1, s1); mrg(m2, s2, m3, s3); mrg(m0, s0, m2, s2);
  float m = m0, s = s0;

#pragma unroll
  for (int off = 32; off; off >>= 1) {
    float om = __shfl_down(m, off), os = __shfl_down(s, off);
    float nm = fmaxf(m, om);
    s = s * __expf(m - nm) + os * __expf(om - nm);
    m = nm;
  }
  __shared__ float sm[16], ssv[16];
  __shared__ float bM, biZ;
  if ((tid & 63) == 0) { sm[tid >> 6] = m; ssv[tid >> 6] = s; }
  __syncthreads();
  if (tid == 0) {
    float M = sm[0], S = ssv[0];
#pragma unroll
    for (int w = 1; w < 16; ++w) {
      float nm = fmaxf(M, sm[w]);
      S = S * __expf(M - nm) + ssv[w] * __expf(sm[w] - nm);
      M = nm;
    }
    bM = M; biZ = 1.f / S;
  }
  __syncthreads();
  const float M = bM, iZ = biZ;
  if (tid < mis) yo[tid] = __expf(x[tid] - M) * iZ;
  float4* y4 = (float4*)(yo + mis);
  for (int i = tid; i < body; i += 1024) {
    float4 v = x4[i];
    float4 o;
    o.x = __expf(v.x - M) * iZ;
    o.y = __expf(v.y - M) * iZ;
    o.z = __expf(v.z - M) * iZ;
    o.w = __expf(v.w - M) * iZ;
    y4[i] = o;
  }
  for (int i = tailoff + tid; i < TVOC; i += 1024)
    yo[i] = __expf(x[i] - M) * iZ;

  // fused gather into grouped layout
  const float gs = EMSCALE * iZ;
  const int rg = r >> 2, rl = r & 3;
  for (int idx = tid; idx < BB * SSEQ; idx += 1024) {
    const int sq = idx >> 5, b = idx & 31;
    const int t = tok[b * SSEQ + sq];
    ems[((size_t)(sq * 128 + rg) * 32 + b) * 4 + rl] =
        __float2bfloat16(__expf(x[t] - M) * gs);
  }
}

// ---------------------------------------------------------------- forward scan
// 2 WGs x 1024 threads (16 waves = 4/SIMD). WG h owns batches [h*16, h*16+16).
// Wave owns j-tile [wave*32, wave*32+32).
// A resident in regs as fp8 e4m3 K=128 fragments.
// alpha fp8 in LDS, double-buffered, CONFLICT-FREE TILED LAYOUT:
//   byte p of (c, h, lane=quad*16+l15) <-> alpha(batch=l15, k=c*128+quad*32+h*16+p)
//   addr = c*2048 + h*1024 + lane*16 + p
// -> B-fragment reads are lane-stride-16 contiguous ds_read_b128 (0 conflicts);
//    writes are 4 B at bank (4*l15+quad)%32 (<=2-way, free).
// Emissions pre-scaled by EMSCALE, grouped [s][j>>2][b][4]; renorm every 16.
__global__ __launch_bounds__(1024) void scan_kernel(
    const float* __restrict__ d_pi, const float* __restrict__ d_A,
    const __hip_bfloat16* __restrict__ ems, float* __restrict__ ws_negll) {
  const int h = blockIdx.x;
  const int tid = threadIdx.x;
  const int lane = tid & 63;
  const int wave = tid >> 6;   // 0..15
  const int l15 = lane & 15;
  const int quad = lane >> 4;  // 0..3
  const int bG = h * 16 + l15; // global batch column

  __shared__ __align__(16) unsigned char alpha[2][8192];
  __shared__ float wmax[16][17];
  __shared__ float wsum[16][17];
  __shared__ float ls[16];

  const uint2* emv = (const uint2*)ems;  // 4 bf16 per uint2

  // ---- resident A fragments: j = wave*32 + n*16 + l15,
  // k byte p of chunk c <-> k = c*128 + quad*32 + p
  v8i aF[2][4];
#pragma unroll
  for (int n = 0; n < 2; ++n) {
    const int jg = wave * 32 + n * 16 + l15;
#pragma unroll
    for (int c = 0; c < 4; ++c) {
#pragma unroll
      for (int g = 0; g < 8; ++g) {
        const int k0 = c * 128 + quad * 32 + g * 4;
        const float v0 = d_A[(size_t)(k0 + 0) * HH + jg] * 512.0f;
        const float v1 = d_A[(size_t)(k0 + 1) * HH + jg] * 512.0f;
        const float v2 = d_A[(size_t)(k0 + 2) * HH + jg] * 512.0f;
        const float v3 = d_A[(size_t)(k0 + 3) * HH + jg] * 512.0f;
        int wrd = 0;
        wrd = __builtin_amdgcn_cvt_pk_fp8_f32(v0, v1, wrd, false);
        wrd = __builtin_amdgcn_cvt_pk_fp8_f32(v2, v3, wrd, true);
        aF[n][c][g] = wrd;
      }
    }
  }

  // ---- t = 0 init: wave w handles batch b=w (global h*16+w)
  {
    const int b = wave;
    const int bb = h * 16 + b;
    const int j0 = lane * 8;
    const float4 p0 = *(const float4*)&d_pi[j0];
    const float4 p1 = *(const float4*)&d_pi[j0 + 4];
    const uint2 e0 = emv[(size_t)(2 * lane) * 32 + bb];
    const uint2 e1 = emv[(size_t)(2 * lane + 1) * 32 + bb];
    float em[8];
    em[0] = __uint_as_float(e0.x << 16);
    em[1] = __uint_as_float(e0.x & 0xFFFF0000u);
    em[2] = __uint_as_float(e0.y << 16);
    em[3] = __uint_as_float(e0.y & 0xFFFF0000u);
    em[4] = __uint_as_float(e1.x << 16);
    em[5] = __uint_as_float(e1.x & 0xFFFF0000u);
    em[6] = __uint_as_float(e1.y << 16);
    em[7] = __uint_as_float(e1.y & 0xFFFF0000u);
    float vals[8];
    vals[0] = (p0.x + EPSF) * em[0];
    vals[1] = (p0.y + EPSF) * em[1];
    vals[2] = (p0.z + EPSF) * em[2];
    vals[3] = (p0.w + EPSF) * em[3];
    vals[4] = (p1.x + EPSF) * em[4];
    vals[5] = (p1.y + EPSF) * em[5];
    vals[6] = (p1.z + EPSF) * em[6];
    vals[7] = (p1.w + EPSF) * em[7];
    float m = -1e30f;
#pragma unroll
    for (int u = 0; u < 8; ++u) m = fmaxf(m, vals[u]);
    m = wave_max(m);
    if (lane == 0) ls[b] = __logf(m);
    const float r = 1.0f / m;
    int lo = 0, hi = 0;
    lo = __builtin_amdgcn_cvt_pk_fp8_f32(vals[0] * r, vals[1] * r, lo, false);
    lo = __builtin_amdgcn_cvt_pk_fp8_f32(vals[2] * r, vals[3] * r, lo, true);
    hi = __builtin_amdgcn_cvt_pk_fp8_f32(vals[4] * r, vals[5] * r, hi, false);
    hi = __builtin_amdgcn_cvt_pk_fp8_f32(vals[6] * r, vals[7] * r, hi, true);
    // tiled layout: k = lane*8+u -> c=lane>>4, h=(lane>>1)&1, quad'=(lane>>2)&3,
    // p = (lane&1)*8 + u ; addr = c*2048 + h*1024 + quad'*256 + b*16 + (lane&1)*8
    const int a0 = (lane >> 4) * 2048 + ((lane >> 1) & 1) * 1024 +
                   ((lane >> 2) & 3) * 256 + b * 16 + (lane & 1) * 8;
    uint2 w2; w2.x = (unsigned)lo; w2.y = (unsigned)hi;
    *(uint2*)&alpha[0][a0] = w2;
  }
  __syncthreads();

  // ---- emission prefetch
  const uint2* ep = emv + ((size_t)1 * 128 + wave * 8 + quad) * 32 + bG;
  uint2 evr[2];
#pragma unroll
  for (int n = 0; n < 2; ++n) evr[n] = ep[n * 128];
  ep += 128 * 32;  // -> s = 2

  // per-thread precomputed offsets
  const int rdoff = lane * 16;  // read base within alpha[buf]
  // write: addr = (w>>2)*2048 + n*1024 + (w&3)*256 + l15*16 + quad*4
  const int wroff = (wave >> 2) * 2048 + (wave & 3) * 256 + l15 * 16 + quad * 4;

#pragma unroll 2
  for (int t = 1; t < SSEQ; ++t) {
    const int cur = (t - 1) & 1, nxt = t & 1;

    // decode this step's emissions (loaded last iteration)
    float ev[2][4];
#pragma unroll
    for (int n = 0; n < 2; ++n) {
      ev[n][0] = __uint_as_float(evr[n].x << 16);
      ev[n][1] = __uint_as_float(evr[n].x & 0xFFFF0000u);
      ev[n][2] = __uint_as_float(evr[n].y << 16);
      ev[n][3] = __uint_as_float(evr[n].y & 0xFFFF0000u);
    }
    // prefetch t+1
#pragma unroll
    for (int n = 0; n < 2; ++n) evr[n] = ep[n * 128];
    if (t <= SSEQ - 3) ep += 128 * 32;

    const unsigned char* ab = &alpha[cur][rdoff];
    f32x4 acc0 = {0.f, 0.f, 0.f, 0.f}, acc1 = {0.f, 0.f, 0.f, 0.f};
#pragma unroll
    for (int c = 0; c < 4; ++c) {
      v8i bf;
      *(int4*)&bf         = *(const int4*)(ab + c * 2048);
      *(((int4*)&bf) + 1) = *(const int4*)(ab + c * 2048 + 1024);
      acc0 = __builtin_amdgcn_mfma_scale_f32_16x16x128_f8f6f4(
          aF[0][c], bf, acc0, 0, 0, 0, 0x7F7F7F7F, 0, 0x7F7F7F7F);
      acc1 = __builtin_amdgcn_mfma_scale_f32_16x16x128_f8f6f4(
          aF[1][c], bf, acc1, 0, 0, 0, 0x7F7F7F7F, 0, 0x7F7F7F7F);
    }

    // D layout: col(b)=lane&15, row(j within subtile)=quad*4+rg
    float y[2][4];
#pragma unroll
    for (int rg = 0; rg < 4; ++rg) {
      y[0][rg] = acc0[rg] * ev[0][rg];
      y[1][rg] = acc1[rg] * ev[1][rg];
    }

    float r = 1.0f;
    if ((t & 15) == 0) {  // renorm: global per-batch max + log accounting
      float mm = -1e30f;
#pragma unroll
      for (int n = 0; n < 2; ++n)
#pragma unroll
        for (int rg = 0; rg < 4; ++rg) mm = fmaxf(mm, y[n][rg]);
      mm = fmaxf(mm, __shfl_xor(mm, 16));
      mm = fmaxf(mm, __shfl_xor(mm, 32));
      if (lane < 16) wmax[wave][lane] = mm;
      __syncthreads();
      float m = wmax[0][l15];
#pragma unroll
      for (int w = 1; w < 16; ++w) m = fmaxf(m, wmax[w][l15]);
      r = 1.0f / m;
      if (tid < 16) ls[tid] += __logf(m);
    }

    {
      unsigned char* aw = &alpha[nxt][wroff];
      int d0 = 0, d1 = 0;
      d0 = __builtin_amdgcn_cvt_pk_fp8_f32(y[0][0] * r, y[0][1] * r, d0, false);
      d0 = __builtin_amdgcn_cvt_pk_fp8_f32(y[0][2] * r, y[0][3] * r, d0, true);
      d1 = __builtin_amdgcn_cvt_pk_fp8_f32(y[1][0] * r, y[1][1] * r, d1, false);
      d1 = __builtin_amdgcn_cvt_pk_fp8_f32(y[1][2] * r, y[1][3] * r, d1, true);
      *(unsigned int*)(aw)        = (unsigned)d0;
      *(unsigned int*)(aw + 1024) = (unsigned)d1;
    }
    if (t == SSEQ - 1) {
      float s = (y[0][0] + y[0][1] + y[0][2] + y[0][3] +
                 y[1][0] + y[1][1] + y[1][2] + y[1][3]) * r;
      s += __shfl_xor(s, 16);
      s += __shfl_xor(s, 32);
      if (lane < 16) wsum[wave][lane] = s;
    }
    __syncthreads();
  }

  if (wave == 0 && lane < 16) {
    float s = 0.f;
#pragma unroll
    for (int w = 0; w < 16; ++w) s += wsum[w][lane];
    const float LL = __logf(s) + ls[lane] - TOTLOG;
    atomicAdd(ws_negll, -LL * (1.0f / 32.0f));
  }
}

// ---------------------------------------------------------------- finalize loss
__global__ __launch_bounds__(512) void finalize_kernel(
    const float* __restrict__ ws, const float* __restrict__ col,
    const float* __restrict__ thr, float* __restrict__ out_loss) {
  const int j = threadIdx.x;
  float v = fmaxf(thr[0] - col[j], 0.f);
  v = wave_sum(v);
  __shared__ float red[8];
  if ((j & 63) == 0) red[j >> 6] = v;
  __syncthreads();
  if (j == 0) {
    float creg = 0.f;
#pragma unroll
    for (int i = 0; i < 8; ++i) creg += red[i];
    out_loss[0] = ws[1] + ws[0] * (0.1f / 512.0f) + creg;
  }
}

// ----------------------------------------------------------------
extern "C" void kernel_launch(void* const* d_in, const int* in_sizes, int n_in,
                              void* d_out, int out_size, void* d_ws, size_t ws_size,
                              hipStream_t stream) {
  const int*   tok    = (const int*)d_in[0];    // [32,256]
  const float* initl  = (const float*)d_in[1];  // [512]
  const float* transl = (const float*)d_in[2];  // [512,512]
  const float* eml    = (const float*)d_in[3];  // [512,50003]
  const float* thr    = (const float*)d_in[4];  // scalar

  float* out      = (float*)d_out;
  float* out_pi   = out;
  float* out_A    = out + HH;
  float* out_B    = out + HH + (size_t)HH * HH;
  float* out_loss = out + HH + (size_t)HH * HH + (size_t)HH * TVOC;

  float* wsf = (float*)d_ws;           // [0..8) scalars, [8..520) col sums
  float* col = wsf + 8;
  __hip_bfloat16* ems = (__hip_bfloat16*)((char*)d_ws + 4096);  // 8.4 MB

  init_ws_kernel<<<1, 512, 0, stream>>>(wsf);
  softmax_pi_kernel<<<1, 512, 0, stream>>>(initl, out_pi);
  softmaxA_kernel<<<512, 512, 0, stream>>>(transl, out_A, wsf + 0);
  colsum_partial_kernel<<<8, 512, 0, stream>>>(out_A, col);
  softmaxB_gather_kernel<<<512, 1024, 0, stream>>>(eml, out_B, tok, ems);
  scan_kernel<<<2, 1024, 0, stream>>>(out_pi, out_A, ems, wsf + 1);
  finalize_kernel<<<1, 512, 0, stream>>>(wsf, col, thr, out_loss);
}

// Round 6
// 567.716 us; speedup vs baseline: 1.1723x; 1.0008x over previous
//
#include <hip/hip_runtime.h>
#include <hip/hip_bf16.h>
#include <stdint.h>

#define HH 512
#define BB 32
#define SSEQ 256
#define TVOC 50003
#define EPSF 1e-10f
#define EMSCALE 96.0f
// 255*ln(512) + 256*ln(96)
#define TOTLOG 2759.2459164008406f

typedef float f32x4 __attribute__((ext_vector_type(4)));
typedef int v8i __attribute__((ext_vector_type(8)));

__device__ __forceinline__ float wave_max(float v) {
#pragma unroll
  for (int off = 32; off; off >>= 1) v = fmaxf(v, __shfl_xor(v, off));
  return v;
}
__device__ __forceinline__ float wave_sum(float v) {
#pragma unroll
  for (int off = 32; off; off >>= 1) v += __shfl_xor(v, off);
  return v;
}

// ---------------------------------------------------------------- ws init
__global__ __launch_bounds__(512) void init_ws_kernel(float* ws) {
  if (threadIdx.x < 8) ws[threadIdx.x] = 0.0f;
  ws[8 + threadIdx.x] = 0.0f;
}

// ---------------------------------------------------------------- pi softmax
__global__ __launch_bounds__(512) void softmax_pi_kernel(
    const float* __restrict__ x, float* __restrict__ pi) {
  const int tid = threadIdx.x;
  const int wv = tid >> 6, ln = tid & 63;
  __shared__ float red[8];
  float v = x[tid];
  float m = wave_max(v);
  if (ln == 0) red[wv] = m;
  __syncthreads();
  float M = red[0];
#pragma unroll
  for (int i = 1; i < 8; ++i) M = fmaxf(M, red[i]);
  float e = __expf(v - M);
  float s = wave_sum(e);
  __syncthreads();
  if (ln == 0) red[wv] = s;
  __syncthreads();
  float S = 0.f;
#pragma unroll
  for (int i = 0; i < 8; ++i) S += red[i];
  pi[tid] = e / S;
}

// ---------------------------------------------------------------- A softmax + entropy
__global__ __launch_bounds__(512) void softmaxA_kernel(
    const float* __restrict__ tl, float* __restrict__ outA,
    float* __restrict__ ws_ent) {
  const int r = blockIdx.x, tid = threadIdx.x;
  const int wv = tid >> 6, ln = tid & 63;
  __shared__ float red[8];
  float v = tl[(size_t)r * HH + tid];
  float m = wave_max(v);
  if (ln == 0) red[wv] = m;
  __syncthreads();
  float M = red[0];
#pragma unroll
  for (int i = 1; i < 8; ++i) M = fmaxf(M, red[i]);
  float e = __expf(v - M);
  float s = wave_sum(e);
  __syncthreads();
  if (ln == 0) red[wv] = s;
  __syncthreads();
  float S = 0.f;
#pragma unroll
  for (int i = 0; i < 8; ++i) S += red[i];
  float p = e / S;
  outA[(size_t)r * HH + tid] = p;
  float ent = -p * __logf(p + EPSF);
  ent = wave_sum(ent);
  __syncthreads();
  if (ln == 0) red[wv] = ent;
  __syncthreads();
  if (tid == 0) {
    float tot = 0.f;
#pragma unroll
    for (int i = 0; i < 8; ++i) tot += red[i];
    atomicAdd(ws_ent, tot);
  }
}

// ---------------------------------------------------------------- partial column sums
__global__ __launch_bounds__(512) void colsum_partial_kernel(
    const float* __restrict__ outA, float* __restrict__ col) {
  const int j = threadIdx.x;
  const int i0 = blockIdx.x * 64;
  float s = 0.f;
#pragma unroll 4
  for (int i = i0; i < i0 + 64; ++i) s += outA[(size_t)i * HH + j];
  atomicAdd(&col[j], s);
}

// ---------------------------------------------------------------- B softmax + fused emission gather
// ems layout (bf16, viewed as uint2 = 4 values): [s][j>>2][b][j&3]
__global__ __launch_bounds__(1024) void softmaxB_gather_kernel(
    const float* __restrict__ el, float* __restrict__ outB,
    const int* __restrict__ tok, __hip_bfloat16* __restrict__ ems) {
  const int r = blockIdx.x, tid = threadIdx.x;
  const float* x = el + (size_t)r * TVOC;
  float* yo = outB + (size_t)r * TVOC;
  const int mis = (int)(((16u - ((unsigned)(uintptr_t)x & 15u)) & 15u) >> 2);
  const int body = (TVOC - mis) >> 2;
  const int tailoff = mis + body * 4;

  // 4 independent online (m,s) chains for ILP
  float m0 = -1e30f, s0 = 0.f, m1 = -1e30f, s1 = 0.f;
  float m2 = -1e30f, s2 = 0.f, m3 = -1e30f, s3 = 0.f;
  auto upd = [](float& m, float& s, float v) {
    if (v > m) { s = s * __expf(m - v) + 1.f; m = v; }
    else       { s += __expf(v - m); }
  };
  if (tid < mis) upd(m0, s0, x[tid]);
  const float4* x4 = (const float4*)(x + mis);
  for (int i = tid; i < body; i += 1024) {
    float4 v = x4[i];
    upd(m0, s0, v.x); upd(m1, s1, v.y); upd(m2, s2, v.z); upd(m3, s3, v.w);
  }
  for (int i = tailoff + tid; i < TVOC; i += 1024) upd(m0, s0, x[i]);
  auto mrg = [](float& m, float& s, float om, float os) {
    float nm = fmaxf(m, om);
    s = s * __expf(m - nm) + os * __expf(om - nm);
    m = nm;
  };
  mrg(m0, s0, m1, s1); mrg(m2, s2, m3, s3); mrg(m0, s0, m2, s2);
  float m = m0, s = s0;

#pragma unroll
  for (int off = 32; off; off >>= 1) {
    float om = __shfl_down(m, off), os = __shfl_down(s, off);
    float nm = fmaxf(m, om);
    s = s * __expf(m - nm) + os * __expf(om - nm);
    m = nm;
  }
  __shared__ float sm[16], ssv[16];
  __shared__ float bM, biZ;
  if ((tid & 63) == 0) { sm[tid >> 6] = m; ssv[tid >> 6] = s; }
  __syncthreads();
  if (tid == 0) {
    float M = sm[0], S = ssv[0];
#pragma unroll
    for (int w = 1; w < 16; ++w) {
      float nm = fmaxf(M, sm[w]);
      S = S * __expf(M - nm) + ssv[w] * __expf(sm[w] - nm);
      M = nm;
    }
    bM = M; biZ = 1.f / S;
  }
  __syncthreads();
  const float M = bM, iZ = biZ;
  if (tid < mis) yo[tid] = __expf(x[tid] - M) * iZ;
  float4* y4 = (float4*)(yo + mis);
  for (int i = tid; i < body; i += 1024) {
    float4 v = x4[i];
    float4 o;
    o.x = __expf(v.x - M) * iZ;
    o.y = __expf(v.y - M) * iZ;
    o.z = __expf(v.z - M) * iZ;
    o.w = __expf(v.w - M) * iZ;
    y4[i] = o;
  }
  for (int i = tailoff + tid; i < TVOC; i += 1024)
    yo[i] = __expf(x[i] - M) * iZ;

  // fused gather into grouped layout
  const float gs = EMSCALE * iZ;
  const int rg = r >> 2, rl = r & 3;
  for (int idx = tid; idx < BB * SSEQ; idx += 1024) {
    const int sq = idx >> 5, b = idx & 31;
    const int t = tok[b * SSEQ + sq];
    ems[((size_t)(sq * 128 + rg) * 32 + b) * 4 + rl] =
        __float2bfloat16(__expf(x[t] - M) * gs);
  }
}

// ---------------------------------------------------------------- forward scan
// 2 WGs x 1024 threads (16 waves = 4/SIMD). WG h owns batches [h*16, h*16+16).
// Wave owns j-tile [wave*32, wave*32+32).
// A resident in regs as fp8 e4m3 K=128 fragments.
// alpha fp8 in LDS, double-buffered, conflict-free tiled layout:
//   byte p of (c, h2, lane=quad*16+l15) <-> alpha(batch=l15, k=c*128+quad*32+h2*16+p)
//   addr = c*2048 + h2*1024 + lane*16 + p
// All 8 ds_read_b128 hoisted to loop head (bf[4] regs) so the LDS pipe is
// saturated while MFMAs run on counted lgkmcnt waits.
// Emissions pre-scaled by EMSCALE, grouped [s][j>>2][b][4]; renorm every 16.
__global__ __launch_bounds__(1024) void scan_kernel(
    const float* __restrict__ d_pi, const float* __restrict__ d_A,
    const __hip_bfloat16* __restrict__ ems, float* __restrict__ ws_negll) {
  const int h = blockIdx.x;
  const int tid = threadIdx.x;
  const int lane = tid & 63;
  const int wave = tid >> 6;   // 0..15
  const int l15 = lane & 15;
  const int quad = lane >> 4;  // 0..3
  const int bG = h * 16 + l15; // global batch column

  __shared__ __align__(16) unsigned char alpha[2][8192];
  __shared__ float wmax[16][17];
  __shared__ float wsum[16][17];
  __shared__ float ls[16];

  const uint2* emv = (const uint2*)ems;  // 4 bf16 per uint2

  // ---- resident A fragments: j = wave*32 + n*16 + l15,
  // k byte p of chunk c <-> k = c*128 + quad*32 + p
  v8i aF[2][4];
#pragma unroll
  for (int n = 0; n < 2; ++n) {
    const int jg = wave * 32 + n * 16 + l15;
#pragma unroll
    for (int c = 0; c < 4; ++c) {
#pragma unroll
      for (int g = 0; g < 8; ++g) {
        const int k0 = c * 128 + quad * 32 + g * 4;
        const float v0 = d_A[(size_t)(k0 + 0) * HH + jg] * 512.0f;
        const float v1 = d_A[(size_t)(k0 + 1) * HH + jg] * 512.0f;
        const float v2 = d_A[(size_t)(k0 + 2) * HH + jg] * 512.0f;
        const float v3 = d_A[(size_t)(k0 + 3) * HH + jg] * 512.0f;
        int wrd = 0;
        wrd = __builtin_amdgcn_cvt_pk_fp8_f32(v0, v1, wrd, false);
        wrd = __builtin_amdgcn_cvt_pk_fp8_f32(v2, v3, wrd, true);
        aF[n][c][g] = wrd;
      }
    }
  }

  // ---- t = 0 init: wave w handles batch b=w (global h*16+w)
  {
    const int b = wave;
    const int bb = h * 16 + b;
    const int j0 = lane * 8;
    const float4 p0 = *(const float4*)&d_pi[j0];
    const float4 p1 = *(const float4*)&d_pi[j0 + 4];
    const uint2 e0 = emv[(size_t)(2 * lane) * 32 + bb];
    const uint2 e1 = emv[(size_t)(2 * lane + 1) * 32 + bb];
    float em[8];
    em[0] = __uint_as_float(e0.x << 16);
    em[1] = __uint_as_float(e0.x & 0xFFFF0000u);
    em[2] = __uint_as_float(e0.y << 16);
    em[3] = __uint_as_float(e0.y & 0xFFFF0000u);
    em[4] = __uint_as_float(e1.x << 16);
    em[5] = __uint_as_float(e1.x & 0xFFFF0000u);
    em[6] = __uint_as_float(e1.y << 16);
    em[7] = __uint_as_float(e1.y & 0xFFFF0000u);
    float vals[8];
    vals[0] = (p0.x + EPSF) * em[0];
    vals[1] = (p0.y + EPSF) * em[1];
    vals[2] = (p0.z + EPSF) * em[2];
    vals[3] = (p0.w + EPSF) * em[3];
    vals[4] = (p1.x + EPSF) * em[4];
    vals[5] = (p1.y + EPSF) * em[5];
    vals[6] = (p1.z + EPSF) * em[6];
    vals[7] = (p1.w + EPSF) * em[7];
    float m = -1e30f;
#pragma unroll
    for (int u = 0; u < 8; ++u) m = fmaxf(m, vals[u]);
    m = wave_max(m);
    if (lane == 0) ls[b] = __logf(m);
    const float r = 1.0f / m;
    int lo = 0, hi = 0;
    lo = __builtin_amdgcn_cvt_pk_fp8_f32(vals[0] * r, vals[1] * r, lo, false);
    lo = __builtin_amdgcn_cvt_pk_fp8_f32(vals[2] * r, vals[3] * r, lo, true);
    hi = __builtin_amdgcn_cvt_pk_fp8_f32(vals[4] * r, vals[5] * r, hi, false);
    hi = __builtin_amdgcn_cvt_pk_fp8_f32(vals[6] * r, vals[7] * r, hi, true);
    // tiled layout: k = lane*8+u -> c=lane>>4, h2=(lane>>1)&1, quad'=(lane>>2)&3,
    // p = (lane&1)*8 + u ; addr = c*2048 + h2*1024 + quad'*256 + b*16 + (lane&1)*8
    const int a0 = (lane >> 4) * 2048 + ((lane >> 1) & 1) * 1024 +
                   ((lane >> 2) & 3) * 256 + b * 16 + (lane & 1) * 8;
    uint2 w2; w2.x = (unsigned)lo; w2.y = (unsigned)hi;
    *(uint2*)&alpha[0][a0] = w2;
  }
  __syncthreads();

  // ---- emission prefetch
  const uint2* ep = emv + ((size_t)1 * 128 + wave * 8 + quad) * 32 + bG;
  uint2 evr[2];
#pragma unroll
  for (int n = 0; n < 2; ++n) evr[n] = ep[n * 128];
  ep += 128 * 32;  // -> s = 2

  // per-thread precomputed offsets
  const int rdoff = lane * 16;  // read base within alpha[buf]
  // write: addr = (w>>2)*2048 + n*1024 + (w&3)*256 + l15*16 + quad*4
  const int wroff = (wave >> 2) * 2048 + (wave & 3) * 256 + l15 * 16 + quad * 4;

#pragma unroll 2
  for (int t = 1; t < SSEQ; ++t) {
    const int cur = (t - 1) & 1, nxt = t & 1;

    // ---- issue ALL 8 alpha reads first: keeps the LDS pipe saturated and
    // lets MFMAs run on counted lgkmcnt waits while later reads fly.
    const unsigned char* ab = &alpha[cur][rdoff];
    v8i bf[4];
#pragma unroll
    for (int c = 0; c < 4; ++c) {
      *(int4*)&bf[c]         = *(const int4*)(ab + c * 2048);
      *(((int4*)&bf[c]) + 1) = *(const int4*)(ab + c * 2048 + 1024);
    }

    // decode this step's emissions (loaded last iteration)
    float ev[2][4];
#pragma unroll
    for (int n = 0; n < 2; ++n) {
      ev[n][0] = __uint_as_float(evr[n].x << 16);
      ev[n][1] = __uint_as_float(evr[n].x & 0xFFFF0000u);
      ev[n][2] = __uint_as_float(evr[n].y << 16);
      ev[n][3] = __uint_as_float(evr[n].y & 0xFFFF0000u);
    }
    // prefetch t+1
#pragma unroll
    for (int n = 0; n < 2; ++n) evr[n] = ep[n * 128];
    if (t <= SSEQ - 3) ep += 128 * 32;

    f32x4 acc0 = {0.f, 0.f, 0.f, 0.f}, acc1 = {0.f, 0.f, 0.f, 0.f};
#pragma unroll
    for (int c = 0; c < 4; ++c) {
      acc0 = __builtin_amdgcn_mfma_scale_f32_16x16x128_f8f6f4(
          aF[0][c], bf[c], acc0, 0, 0, 0, 0x7F7F7F7F, 0, 0x7F7F7F7F);
      acc1 = __builtin_amdgcn_mfma_scale_f32_16x16x128_f8f6f4(
          aF[1][c], bf[c], acc1, 0, 0, 0, 0x7F7F7F7F, 0, 0x7F7F7F7F);
    }

    // D layout: col(b)=lane&15, row(j within subtile)=quad*4+rg
    float y[2][4];
#pragma unroll
    for (int rg = 0; rg < 4; ++rg) {
      y[0][rg] = acc0[rg] * ev[0][rg];
      y[1][rg] = acc1[rg] * ev[1][rg];
    }

    float r = 1.0f;
    if ((t & 15) == 0) {  // renorm: global per-batch max + log accounting
      float mm = -1e30f;
#pragma unroll
      for (int n = 0; n < 2; ++n)
#pragma unroll
        for (int rg = 0; rg < 4; ++rg) mm = fmaxf(mm, y[n][rg]);
      mm = fmaxf(mm, __shfl_xor(mm, 16));
      mm = fmaxf(mm, __shfl_xor(mm, 32));
      if (lane < 16) wmax[wave][lane] = mm;
      __syncthreads();
      float m = wmax[0][l15];
#pragma unroll
      for (int w = 1; w < 16; ++w) m = fmaxf(m, wmax[w][l15]);
      r = 1.0f / m;
      if (tid < 16) ls[tid] += __logf(m);
    }

    {
      unsigned char* aw = &alpha[nxt][wroff];
      int d0 = 0, d1 = 0;
      d0 = __builtin_amdgcn_cvt_pk_fp8_f32(y[0][0] * r, y[0][1] * r, d0, false);
      d0 = __builtin_amdgcn_cvt_pk_fp8_f32(y[0][2] * r, y[0][3] * r, d0, true);
      d1 = __builtin_amdgcn_cvt_pk_fp8_f32(y[1][0] * r, y[1][1] * r, d1, false);
      d1 = __builtin_amdgcn_cvt_pk_fp8_f32(y[1][2] * r, y[1][3] * r, d1, true);
      *(unsigned int*)(aw)        = (unsigned)d0;
      *(unsigned int*)(aw + 1024) = (unsigned)d1;
    }
    if (t == SSEQ - 1) {
      float s = (y[0][0] + y[0][1] + y[0][2] + y[0][3] +
                 y[1][0] + y[1][1] + y[1][2] + y[1][3]) * r;
      s += __shfl_xor(s, 16);
      s += __shfl_xor(s, 32);
      if (lane < 16) wsum[wave][lane] = s;
    }
    __syncthreads();
  }

  if (wave == 0 && lane < 16) {
    float s = 0.f;
#pragma unroll
    for (int w = 0; w < 16; ++w) s += wsum[w][lane];
    const float LL = __logf(s) + ls[lane] - TOTLOG;
    atomicAdd(ws_negll, -LL * (1.0f / 32.0f));
  }
}

// ---------------------------------------------------------------- finalize loss
__global__ __launch_bounds__(512) void finalize_kernel(
    const float* __restrict__ ws, const float* __restrict__ col,
    const float* __restrict__ thr, float* __restrict__ out_loss) {
  const int j = threadIdx.x;
  float v = fmaxf(thr[0] - col[j], 0.f);
  v = wave_sum(v);
  __shared__ float red[8];
  if ((j & 63) == 0) red[j >> 6] = v;
  __syncthreads();
  if (j == 0) {
    float creg = 0.f;
#pragma unroll
    for (int i = 0; i < 8; ++i) creg += red[i];
    out_loss[0] = ws[1] + ws[0] * (0.1f / 512.0f) + creg;
  }
}

// ----------------------------------------------------------------
extern "C" void kernel_launch(void* const* d_in, const int* in_sizes, int n_in,
                              void* d_out, int out_size, void* d_ws, size_t ws_size,
                              hipStream_t stream) {
  const int*   tok    = (const int*)d_in[0];    // [32,256]
  const float* initl  = (const float*)d_in[1];  // [512]
  const float* transl = (const float*)d_in[2];  // [512,512]
  const float* eml    = (const float*)d_in[3];  // [512,50003]
  const float* thr    = (const float*)d_in[4];  // scalar

  float* out      = (float*)d_out;
  float* out_pi   = out;
  float* out_A    = out + HH;
  float* out_B    = out + HH + (size_t)HH * HH;
  float* out_loss = out + HH + (size_t)HH * HH + (size_t)HH * TVOC;

  float* wsf = (float*)d_ws;           // [0..8) scalars, [8..520) col sums
  float* col = wsf + 8;
  __hip_bfloat16* ems = (__hip_bfloat16*)((char*)d_ws + 4096);  // 8.4 MB

  init_ws_kernel<<<1, 512, 0, stream>>>(wsf);
  softmax_pi_kernel<<<1, 512, 0, stream>>>(initl, out_pi);
  softmaxA_kernel<<<512, 512, 0, stream>>>(transl, out_A, wsf + 0);
  colsum_partial_kernel<<<8, 512, 0, stream>>>(out_A, col);
  softmaxB_gather_kernel<<<512, 1024, 0, stream>>>(eml, out_B, tok, ems);
  scan_kernel<<<2, 1024, 0, stream>>>(out_pi, out_A, ems, wsf + 1);
  finalize_kernel<<<1, 512, 0, stream>>>(wsf, col, thr, out_loss);
}

// Round 7
// 547.287 us; speedup vs baseline: 1.2161x; 1.0373x over previous
//
#include <hip/hip_runtime.h>
#include <hip/hip_bf16.h>
#include <stdint.h>

#define HH 512
#define BB 32
#define SSEQ 256
#define TVOC 50003
#define EPSF 1e-10f
#define EMSCALE 96.0f
// 255*ln(512) + 256*ln(96)
#define TOTLOG 2759.2459164008406f

typedef float f32x4 __attribute__((ext_vector_type(4)));
typedef int v8i __attribute__((ext_vector_type(8)));

__device__ __forceinline__ float wave_max(float v) {
#pragma unroll
  for (int off = 32; off; off >>= 1) v = fmaxf(v, __shfl_xor(v, off));
  return v;
}
__device__ __forceinline__ float wave_sum(float v) {
#pragma unroll
  for (int off = 32; off; off >>= 1) v += __shfl_xor(v, off);
  return v;
}

// LDS-publish barrier: drain LDS ops, raw barrier, no vmcnt drain so global
// prefetches stay in flight across steps (T4: never vmcnt(0) in main loop).
__device__ __forceinline__ void bar_lds() {
  asm volatile("s_waitcnt lgkmcnt(0)" ::: "memory");
  __builtin_amdgcn_s_barrier();
  __builtin_amdgcn_sched_barrier(0);
}

// ---------------------------------------------------------------- ws init
__global__ __launch_bounds__(512) void init_ws_kernel(float* ws) {
  if (threadIdx.x < 8) ws[threadIdx.x] = 0.0f;
  ws[8 + threadIdx.x] = 0.0f;
}

// ---------------------------------------------------------------- pi softmax
__global__ __launch_bounds__(512) void softmax_pi_kernel(
    const float* __restrict__ x, float* __restrict__ pi) {
  const int tid = threadIdx.x;
  const int wv = tid >> 6, ln = tid & 63;
  __shared__ float red[8];
  float v = x[tid];
  float m = wave_max(v);
  if (ln == 0) red[wv] = m;
  __syncthreads();
  float M = red[0];
#pragma unroll
  for (int i = 1; i < 8; ++i) M = fmaxf(M, red[i]);
  float e = __expf(v - M);
  float s = wave_sum(e);
  __syncthreads();
  if (ln == 0) red[wv] = s;
  __syncthreads();
  float S = 0.f;
#pragma unroll
  for (int i = 0; i < 8; ++i) S += red[i];
  pi[tid] = e / S;
}

// ---------------------------------------------------------------- A softmax + entropy
__global__ __launch_bounds__(512) void softmaxA_kernel(
    const float* __restrict__ tl, float* __restrict__ outA,
    float* __restrict__ ws_ent) {
  const int r = blockIdx.x, tid = threadIdx.x;
  const int wv = tid >> 6, ln = tid & 63;
  __shared__ float red[8];
  float v = tl[(size_t)r * HH + tid];
  float m = wave_max(v);
  if (ln == 0) red[wv] = m;
  __syncthreads();
  float M = red[0];
#pragma unroll
  for (int i = 1; i < 8; ++i) M = fmaxf(M, red[i]);
  float e = __expf(v - M);
  float s = wave_sum(e);
  __syncthreads();
  if (ln == 0) red[wv] = s;
  __syncthreads();
  float S = 0.f;
#pragma unroll
  for (int i = 0; i < 8; ++i) S += red[i];
  float p = e / S;
  outA[(size_t)r * HH + tid] = p;
  float ent = -p * __logf(p + EPSF);
  ent = wave_sum(ent);
  __syncthreads();
  if (ln == 0) red[wv] = ent;
  __syncthreads();
  if (tid == 0) {
    float tot = 0.f;
#pragma unroll
    for (int i = 0; i < 8; ++i) tot += red[i];
    atomicAdd(ws_ent, tot);
  }
}

// ---------------------------------------------------------------- partial column sums
__global__ __launch_bounds__(512) void colsum_partial_kernel(
    const float* __restrict__ outA, float* __restrict__ col) {
  const int j = threadIdx.x;
  const int i0 = blockIdx.x * 64;
  float s = 0.f;
#pragma unroll 4
  for (int i = i0; i < i0 + 64; ++i) s += outA[(size_t)i * HH + j];
  atomicAdd(&col[j], s);
}

// ---------------------------------------------------------------- B softmax + fused emission gather
// ems layout (bf16, viewed as uint2 = 4 values): [s][j>>2][b][j&3]
__global__ __launch_bounds__(1024) void softmaxB_gather_kernel(
    const float* __restrict__ el, float* __restrict__ outB,
    const int* __restrict__ tok, __hip_bfloat16* __restrict__ ems) {
  const int r = blockIdx.x, tid = threadIdx.x;
  const float* x = el + (size_t)r * TVOC;
  float* yo = outB + (size_t)r * TVOC;
  const int mis = (int)(((16u - ((unsigned)(uintptr_t)x & 15u)) & 15u) >> 2);
  const int body = (TVOC - mis) >> 2;
  const int tailoff = mis + body * 4;

  // 4 independent online (m,s) chains for ILP
  float m0 = -1e30f, s0 = 0.f, m1 = -1e30f, s1 = 0.f;
  float m2 = -1e30f, s2 = 0.f, m3 = -1e30f, s3 = 0.f;
  auto upd = [](float& m, float& s, float v) {
    if (v > m) { s = s * __expf(m - v) + 1.f; m = v; }
    else       { s += __expf(v - m); }
  };
  if (tid < mis) upd(m0, s0, x[tid]);
  const float4* x4 = (const float4*)(x + mis);
  for (int i = tid; i < body; i += 1024) {
    float4 v = x4[i];
    upd(m0, s0, v.x); upd(m1, s1, v.y); upd(m2, s2, v.z); upd(m3, s3, v.w);
  }
  for (int i = tailoff + tid; i < TVOC; i += 1024) upd(m0, s0, x[i]);
  auto mrg = [](float& m, float& s, float om, float os) {
    float nm = fmaxf(m, om);
    s = s * __expf(m - nm) + os * __expf(om - nm);
    m = nm;
  };
  mrg(m0, s0, m1, s1); mrg(m2, s2, m3, s3); mrg(m0, s0, m2, s2);
  float m = m0, s = s0;

#pragma unroll
  for (int off = 32; off; off >>= 1) {
    float om = __shfl_down(m, off), os = __shfl_down(s, off);
    float nm = fmaxf(m, om);
    s = s * __expf(m - nm) + os * __expf(om - nm);
    m = nm;
  }
  __shared__ float sm[16], ssv[16];
  __shared__ float bM, biZ;
  if ((tid & 63) == 0) { sm[tid >> 6] = m; ssv[tid >> 6] = s; }
  __syncthreads();
  if (tid == 0) {
    float M = sm[0], S = ssv[0];
#pragma unroll
    for (int w = 1; w < 16; ++w) {
      float nm = fmaxf(M, sm[w]);
      S = S * __expf(M - nm) + ssv[w] * __expf(sm[w] - nm);
      M = nm;
    }
    bM = M; biZ = 1.f / S;
  }
  __syncthreads();
  const float M = bM, iZ = biZ;
  if (tid < mis) yo[tid] = __expf(x[tid] - M) * iZ;
  float4* y4 = (float4*)(yo + mis);
  for (int i = tid; i < body; i += 1024) {
    float4 v = x4[i];
    float4 o;
    o.x = __expf(v.x - M) * iZ;
    o.y = __expf(v.y - M) * iZ;
    o.z = __expf(v.z - M) * iZ;
    o.w = __expf(v.w - M) * iZ;
    y4[i] = o;
  }
  for (int i = tailoff + tid; i < TVOC; i += 1024)
    yo[i] = __expf(x[i] - M) * iZ;

  // fused gather into grouped layout
  const float gs = EMSCALE * iZ;
  const int rg = r >> 2, rl = r & 3;
  for (int idx = tid; idx < BB * SSEQ; idx += 1024) {
    const int sq = idx >> 5, b = idx & 31;
    const int t = tok[b * SSEQ + sq];
    ems[((size_t)(sq * 128 + rg) * 32 + b) * 4 + rl] =
        __float2bfloat16(__expf(x[t] - M) * gs);
  }
}

// ---------------------------------------------------------------- forward scan
// 2 WGs x 1024 threads (16 waves = 4/SIMD). WG h owns batches [h*16, h*16+16).
// Wave owns j-tile [wave*32, wave*32+32).
// A resident in regs as fp8 e4m3 K=128 fragments.
// alpha fp8 in LDS, double-buffered, conflict-free tiled layout:
//   byte p of (c, h2, lane=quad*16+l15) <-> alpha(batch=l15, k=c*128+quad*32+h2*16+p)
// Steps separated by lgkm-only barriers (bar_lds) so emission prefetch
// global loads stay in flight across steps.
// Renorm every 16 steps uses STALE per-wave maxes published one step early
// (t&15==15), so the renorm step needs no extra barrier; scale remains
// per-batch-uniform across waves (correctness requirement).
__global__ __launch_bounds__(1024) void scan_kernel(
    const float* __restrict__ d_pi, const float* __restrict__ d_A,
    const __hip_bfloat16* __restrict__ ems, float* __restrict__ ws_negll) {
  const int h = blockIdx.x;
  const int tid = threadIdx.x;
  const int lane = tid & 63;
  const int wave = tid >> 6;   // 0..15
  const int l15 = lane & 15;
  const int quad = lane >> 4;  // 0..3
  const int bG = h * 16 + l15; // global batch column

  __shared__ __align__(16) unsigned char alpha[2][8192];
  __shared__ float wmax[16][17];
  __shared__ float wsum[16][17];
  __shared__ float ls[16];

  const uint2* emv = (const uint2*)ems;  // 4 bf16 per uint2

  // ---- resident A fragments: j = wave*32 + n*16 + l15,
  // k byte p of chunk c <-> k = c*128 + quad*32 + p
  v8i aF[2][4];
#pragma unroll
  for (int n = 0; n < 2; ++n) {
    const int jg = wave * 32 + n * 16 + l15;
#pragma unroll
    for (int c = 0; c < 4; ++c) {
#pragma unroll
      for (int g = 0; g < 8; ++g) {
        const int k0 = c * 128 + quad * 32 + g * 4;
        const float v0 = d_A[(size_t)(k0 + 0) * HH + jg] * 512.0f;
        const float v1 = d_A[(size_t)(k0 + 1) * HH + jg] * 512.0f;
        const float v2 = d_A[(size_t)(k0 + 2) * HH + jg] * 512.0f;
        const float v3 = d_A[(size_t)(k0 + 3) * HH + jg] * 512.0f;
        int wrd = 0;
        wrd = __builtin_amdgcn_cvt_pk_fp8_f32(v0, v1, wrd, false);
        wrd = __builtin_amdgcn_cvt_pk_fp8_f32(v2, v3, wrd, true);
        aF[n][c][g] = wrd;
      }
    }
  }

  // ---- t = 0 init: wave w handles batch b=w (global h*16+w)
  {
    const int b = wave;
    const int bb = h * 16 + b;
    const int j0 = lane * 8;
    const float4 p0 = *(const float4*)&d_pi[j0];
    const float4 p1 = *(const float4*)&d_pi[j0 + 4];
    const uint2 e0 = emv[(size_t)(2 * lane) * 32 + bb];
    const uint2 e1 = emv[(size_t)(2 * lane + 1) * 32 + bb];
    float em[8];
    em[0] = __uint_as_float(e0.x << 16);
    em[1] = __uint_as_float(e0.x & 0xFFFF0000u);
    em[2] = __uint_as_float(e0.y << 16);
    em[3] = __uint_as_float(e0.y & 0xFFFF0000u);
    em[4] = __uint_as_float(e1.x << 16);
    em[5] = __uint_as_float(e1.x & 0xFFFF0000u);
    em[6] = __uint_as_float(e1.y << 16);
    em[7] = __uint_as_float(e1.y & 0xFFFF0000u);
    float vals[8];
    vals[0] = (p0.x + EPSF) * em[0];
    vals[1] = (p0.y + EPSF) * em[1];
    vals[2] = (p0.z + EPSF) * em[2];
    vals[3] = (p0.w + EPSF) * em[3];
    vals[4] = (p1.x + EPSF) * em[4];
    vals[5] = (p1.y + EPSF) * em[5];
    vals[6] = (p1.z + EPSF) * em[6];
    vals[7] = (p1.w + EPSF) * em[7];
    float m = -1e30f;
#pragma unroll
    for (int u = 0; u < 8; ++u) m = fmaxf(m, vals[u]);
    m = wave_max(m);
    if (lane == 0) ls[b] = __logf(m);
    const float r = 1.0f / m;
    int lo = 0, hi = 0;
    lo = __builtin_amdgcn_cvt_pk_fp8_f32(vals[0] * r, vals[1] * r, lo, false);
    lo = __builtin_amdgcn_cvt_pk_fp8_f32(vals[2] * r, vals[3] * r, lo, true);
    hi = __builtin_amdgcn_cvt_pk_fp8_f32(vals[4] * r, vals[5] * r, hi, false);
    hi = __builtin_amdgcn_cvt_pk_fp8_f32(vals[6] * r, vals[7] * r, hi, true);
    // tiled layout: k = lane*8+u -> c=lane>>4, h2=(lane>>1)&1, quad'=(lane>>2)&3,
    // p = (lane&1)*8 + u ; addr = c*2048 + h2*1024 + quad'*256 + b*16 + (lane&1)*8
    const int a0 = (lane >> 4) * 2048 + ((lane >> 1) & 1) * 1024 +
                   ((lane >> 2) & 3) * 256 + b * 16 + (lane & 1) * 8;
    uint2 w2; w2.x = (unsigned)lo; w2.y = (unsigned)hi;
    *(uint2*)&alpha[0][a0] = w2;
  }
  __syncthreads();

  // ---- emission prefetch
  const uint2* ep = emv + ((size_t)1 * 128 + wave * 8 + quad) * 32 + bG;
  uint2 evr[2];
#pragma unroll
  for (int n = 0; n < 2; ++n) evr[n] = ep[n * 128];
  ep += 128 * 32;  // -> s = 2

  // per-thread precomputed offsets
  const int rdoff = lane * 16;  // read base within alpha[buf]
  // write: addr = (w>>2)*2048 + n*1024 + (w&3)*256 + l15*16 + quad*4
  const int wroff = (wave >> 2) * 2048 + (wave & 3) * 256 + l15 * 16 + quad * 4;

  auto packpair = [](float a, float b, float c, float d) {
    int v = 0;
    v = __builtin_amdgcn_cvt_pk_fp8_f32(a, b, v, false);
    v = __builtin_amdgcn_cvt_pk_fp8_f32(c, d, v, true);
    return (unsigned)v;
  };

#pragma unroll 2
  for (int t = 1; t < SSEQ; ++t) {
    const int cur = (t - 1) & 1, nxt = t & 1;

    // issue all 8 alpha reads
    const unsigned char* ab = &alpha[cur][rdoff];
    v8i bf[4];
#pragma unroll
    for (int c = 0; c < 4; ++c) {
      *(int4*)&bf[c]         = *(const int4*)(ab + c * 2048);
      *(((int4*)&bf[c]) + 1) = *(const int4*)(ab + c * 2048 + 1024);
    }

    // decode this step's emissions (loaded last iteration)
    float ev[2][4];
#pragma unroll
    for (int n = 0; n < 2; ++n) {
      ev[n][0] = __uint_as_float(evr[n].x << 16);
      ev[n][1] = __uint_as_float(evr[n].x & 0xFFFF0000u);
      ev[n][2] = __uint_as_float(evr[n].y << 16);
      ev[n][3] = __uint_as_float(evr[n].y & 0xFFFF0000u);
    }
    // prefetch t+1 (rides across the lgkm-only barrier)
#pragma unroll
    for (int n = 0; n < 2; ++n) evr[n] = ep[n * 128];
    if (t <= SSEQ - 3) ep += 128 * 32;

    f32x4 acc0 = {0.f, 0.f, 0.f, 0.f}, acc1 = {0.f, 0.f, 0.f, 0.f};
#pragma unroll
    for (int c = 0; c < 4; ++c) {
      acc0 = __builtin_amdgcn_mfma_scale_f32_16x16x128_f8f6f4(
          aF[0][c], bf[c], acc0, 0, 0, 0, 0x7F7F7F7F, 0, 0x7F7F7F7F);
      acc1 = __builtin_amdgcn_mfma_scale_f32_16x16x128_f8f6f4(
          aF[1][c], bf[c], acc1, 0, 0, 0, 0x7F7F7F7F, 0, 0x7F7F7F7F);
    }

    // D layout: col(b)=lane&15, row(j within subtile)=quad*4+rg
    float y[2][4];
#pragma unroll
    for (int rg = 0; rg < 4; ++rg) {
      y[0][rg] = acc0[rg] * ev[0][rg];
      y[1][rg] = acc1[rg] * ev[1][rg];
    }

    unsigned char* aw = &alpha[nxt][wroff];
    if ((t & 15) == 0) {
      // renorm step: use STALE per-wave maxes published at t-1 (visible after
      // last barrier); per-batch-uniform scale; no extra barrier needed.
      float m = wmax[0][l15];
#pragma unroll
      for (int w = 1; w < 16; ++w) m = fmaxf(m, wmax[w][l15]);
      const float r = 1.0f / m;
      if (tid < 16) ls[tid] += __logf(m);
      *(unsigned*)(aw) =
          packpair(y[0][0] * r, y[0][1] * r, y[0][2] * r, y[0][3] * r);
      *(unsigned*)(aw + 1024) =
          packpair(y[1][0] * r, y[1][1] * r, y[1][2] * r, y[1][3] * r);
    } else {
      if ((t & 15) == 15) {
        // publish wave-local per-batch max for next step's renorm
        float mm = -1e30f;
#pragma unroll
        for (int n = 0; n < 2; ++n)
#pragma unroll
          for (int rg = 0; rg < 4; ++rg) mm = fmaxf(mm, y[n][rg]);
        mm = fmaxf(mm, __shfl_xor(mm, 16));
        mm = fmaxf(mm, __shfl_xor(mm, 32));
        if (lane < 16) wmax[wave][lane] = mm;
      }
      *(unsigned*)(aw) = packpair(y[0][0], y[0][1], y[0][2], y[0][3]);
      *(unsigned*)(aw + 1024) = packpair(y[1][0], y[1][1], y[1][2], y[1][3]);
    }

    if (t == SSEQ - 1) {
      float s = (y[0][0] + y[0][1] + y[0][2] + y[0][3] +
                 y[1][0] + y[1][1] + y[1][2] + y[1][3]);
      s += __shfl_xor(s, 16);
      s += __shfl_xor(s, 32);
      if (lane < 16) wsum[wave][lane] = s;
    }
    bar_lds();
  }

  if (wave == 0 && lane < 16) {
    float s = 0.f;
#pragma unroll
    for (int w = 0; w < 16; ++w) s += wsum[w][lane];
    const float LL = __logf(s) + ls[lane] - TOTLOG;
    atomicAdd(ws_negll, -LL * (1.0f / 32.0f));
  }
}

// ---------------------------------------------------------------- finalize loss
__global__ __launch_bounds__(512) void finalize_kernel(
    const float* __restrict__ ws, const float* __restrict__ col,
    const float* __restrict__ thr, float* __restrict__ out_loss) {
  const int j = threadIdx.x;
  float v = fmaxf(thr[0] - col[j], 0.f);
  v = wave_sum(v);
  __shared__ float red[8];
  if ((j & 63) == 0) red[j >> 6] = v;
  __syncthreads();
  if (j == 0) {
    float creg = 0.f;
#pragma unroll
    for (int i = 0; i < 8; ++i) creg += red[i];
    out_loss[0] = ws[1] + ws[0] * (0.1f / 512.0f) + creg;
  }
}

// ----------------------------------------------------------------
extern "C" void kernel_launch(void* const* d_in, const int* in_sizes, int n_in,
                              void* d_out, int out_size, void* d_ws, size_t ws_size,
                              hipStream_t stream) {
  const int*   tok    = (const int*)d_in[0];    // [32,256]
  const float* initl  = (const float*)d_in[1];  // [512]
  const float* transl = (const float*)d_in[2];  // [512,512]
  const float* eml    = (const float*)d_in[3];  // [512,50003]
  const float* thr    = (const float*)d_in[4];  // scalar

  float* out      = (float*)d_out;
  float* out_pi   = out;
  float* out_A    = out + HH;
  float* out_B    = out + HH + (size_t)HH * HH;
  float* out_loss = out + HH + (size_t)HH * HH + (size_t)HH * TVOC;

  float* wsf = (float*)d_ws;           // [0..8) scalars, [8..520) col sums
  float* col = wsf + 8;
  __hip_bfloat16* ems = (__hip_bfloat16*)((char*)d_ws + 4096);  // 8.4 MB

  init_ws_kernel<<<1, 512, 0, stream>>>(wsf);
  softmax_pi_kernel<<<1, 512, 0, stream>>>(initl, out_pi);
  softmaxA_kernel<<<512, 512, 0, stream>>>(transl, out_A, wsf + 0);
  colsum_partial_kernel<<<8, 512, 0, stream>>>(out_A, col);
  softmaxB_gather_kernel<<<512, 1024, 0, stream>>>(eml, out_B, tok, ems);
  scan_kernel<<<2, 1024, 0, stream>>>(out_pi, out_A, ems, wsf + 1);
  finalize_kernel<<<1, 512, 0, stream>>>(wsf, col, thr, out_loss);
}